// Round 1
// baseline (588.807 us; speedup 1.0000x reference)
//
#include <hip/hip_runtime.h>
#include <hip/hip_bf16.h>

#define N_NODES   100000
#define N_EDGES   1600000
#define NUM_GRAPHS 1024
#define D         128
#define LN_EPS    1e-5f
#define NSCAN_BLK 391   // ceil(100000/256)

typedef __attribute__((ext_vector_type(8))) short short8;
typedef __attribute__((ext_vector_type(4))) float floatx4;

static __device__ __forceinline__ float bf2f(unsigned int u) {
    return __uint_as_float(u << 16);
}
static __device__ __forceinline__ unsigned short f2bf(float f) {
    __hip_bfloat16 h = __float2bfloat16(f);
    return *reinterpret_cast<unsigned short*>(&h);
}

// ---- weight prep: Wcat[c][k] = k<128 ? Wl[c][k] : Wr[c][k-128], fp32 -> bf16 ----
__global__ void cvt_weights_kernel(const float* __restrict__ W1l, const float* __restrict__ W1r,
                                   const float* __restrict__ W2l, const float* __restrict__ W2r,
                                   unsigned short* __restrict__ Wc1, unsigned short* __restrict__ Wc2) {
    int idx = blockIdx.x * 256 + threadIdx.x;   // 0..65535 (2 layers x 128 x 256)
    int layer = idx >> 15;
    int rem = idx & 32767;
    int c = rem >> 8;
    int k = rem & 255;
    const float* Wl = layer ? W2l : W1l;
    const float* Wr = layer ? W2r : W1r;
    unsigned short* dst = layer ? Wc2 : Wc1;
    float v = (k < 128) ? Wl[c * 128 + k] : Wr[c * 128 + (k - 128)];
    dst[c * 256 + k] = f2bf(v);
}

// ---- x fp32 -> bf16 (vectorized float4 -> ushort4) ----
__global__ void cvt_x_kernel(const float* __restrict__ x, unsigned short* __restrict__ xbf) {
    int i = blockIdx.x * 256 + threadIdx.x;     // float4 index, 3.2M exact
    float4 v = reinterpret_cast<const float4*>(x)[i];
    ushort4 o;
    o.x = f2bf(v.x); o.y = f2bf(v.y); o.z = f2bf(v.z); o.w = f2bf(v.w);
    reinterpret_cast<ushort4*>(xbf)[i] = o;
}

// ---- CSR build ----
__global__ void hist_kernel(const int* __restrict__ dst, int* __restrict__ deg) {
    int e = blockIdx.x * 256 + threadIdx.x;     // grid exact (6250*256 = 1.6M)
    atomicAdd(&deg[dst[e]], 1);
}

__global__ void scan1_kernel(const int* __restrict__ deg, int* __restrict__ bsum) {
    __shared__ int s[256];
    int i = blockIdx.x * 256 + threadIdx.x;
    int v = (i < N_NODES) ? deg[i] : 0;
    s[threadIdx.x] = v;
    __syncthreads();
    for (int off = 128; off > 0; off >>= 1) {
        if (threadIdx.x < off) s[threadIdx.x] += s[threadIdx.x + off];
        __syncthreads();
    }
    if (threadIdx.x == 0) bsum[blockIdx.x] = s[0];
}

__global__ void scan2_kernel(const int* __restrict__ bsum, int* __restrict__ boff,
                             int* __restrict__ row_start) {
    __shared__ int s[512];
    int t = threadIdx.x;
    int v = (t < NSCAN_BLK) ? bsum[t] : 0;
    s[t] = v;
    __syncthreads();
    for (int off = 1; off < 512; off <<= 1) {
        int add = (t >= off) ? s[t - off] : 0;
        __syncthreads();
        s[t] += add;
        __syncthreads();
    }
    if (t < NSCAN_BLK) boff[t] = s[t] - v;              // exclusive
    if (t == NSCAN_BLK - 1) row_start[N_NODES] = s[t];  // == N_EDGES
}

__global__ void scan3_kernel(const int* __restrict__ deg, const int* __restrict__ boff,
                             int* __restrict__ row_start, int* __restrict__ cursor) {
    __shared__ int s[256];
    int t = threadIdx.x;
    int i = blockIdx.x * 256 + t;
    int v = (i < N_NODES) ? deg[i] : 0;
    s[t] = v;
    __syncthreads();
    for (int off = 1; off < 256; off <<= 1) {
        int add = (t >= off) ? s[t - off] : 0;
        __syncthreads();
        s[t] += add;
        __syncthreads();
    }
    if (i < N_NODES) {
        int rs = boff[blockIdx.x] + s[t] - v;           // exclusive prefix
        row_start[i] = rs;
        cursor[i] = rs;
    }
}

__global__ void scatter_kernel(const int* __restrict__ src, const int* __restrict__ dst,
                               int* __restrict__ cursor, int* __restrict__ src_sorted) {
    int e = blockIdx.x * 256 + threadIdx.x;
    int d = dst[e];
    int p = atomicAdd(&cursor[d], 1);
    src_sorted[p] = src[e];
}

// ---- mean aggregation by gather: one wave per node, lane holds 2 channels ----
__global__ void aggregate_kernel(const unsigned short* __restrict__ feat,
                                 const int* __restrict__ src_sorted,
                                 const int* __restrict__ row_start,
                                 unsigned short* __restrict__ aggout) {
    int wave = threadIdx.x >> 6;
    int lane = threadIdx.x & 63;
    int node = blockIdx.x * 4 + wave;
    if (node >= N_NODES) return;
    int s = row_start[node];
    int e = row_start[node + 1];
    float ax = 0.f, ay = 0.f;
    int j = s;
    for (; j + 1 < e; j += 2) {   // unroll x2 for MLP
        int u0 = src_sorted[j];
        int u1 = src_sorted[j + 1];
        unsigned int v0 = *(const unsigned int*)(feat + u0 * 128 + lane * 2);
        unsigned int v1 = *(const unsigned int*)(feat + u1 * 128 + lane * 2);
        ax += bf2f(v0 & 0xffffu) + bf2f(v1 & 0xffffu);
        ay += bf2f(v0 >> 16)     + bf2f(v1 >> 16);
    }
    if (j < e) {
        int u = src_sorted[j];
        unsigned int v = *(const unsigned int*)(feat + u * 128 + lane * 2);
        ax += bf2f(v & 0xffffu);
        ay += bf2f(v >> 16);
    }
    int dgi = e - s;
    float inv = 1.f / (float)(dgi > 1 ? dgi : 1);
    unsigned int packed = (unsigned int)f2bf(ax * inv) | ((unsigned int)f2bf(ay * inv) << 16);
    *(unsigned int*)(aggout + node * 128 + lane * 2) = packed;
}

// ---- fused SAGE linear: out = relu([A1|A2] @ Wcat^T + bias), bf16 MFMA ----
// M-tile 64 nodes x all 128 cols per block; wave w covers cols [32w, 32w+32).
__global__ __launch_bounds__(256)
void gemm_kernel(const unsigned short* __restrict__ A1,   // k 0..127   (agg)
                 const unsigned short* __restrict__ A2,   // k 128..255 (self)
                 const unsigned short* __restrict__ Wcat, // [128][256] bf16 (B^T form)
                 const float* __restrict__ bias,
                 unsigned short* __restrict__ out) {
    __shared__ unsigned short Asm[64][32];    // 4 KB
    __shared__ unsigned short Wsm[128][32];   // 8 KB
    int tid = threadIdx.x;
    int wave = tid >> 6;
    int lane = tid & 63;
    int nodeBase = blockIdx.x * 64;
    floatx4 acc[4][2];
    #pragma unroll
    for (int a = 0; a < 4; ++a)
        #pragma unroll
        for (int b = 0; b < 2; ++b) acc[a][b] = (floatx4){0.f, 0.f, 0.f, 0.f};

    int r = tid >> 2, sg = tid & 3;           // A staging: 64 rows x 4 x 16B
    int quad = lane >> 4, m = lane & 15;

    for (int kc = 0; kc < 8; ++kc) {
        const unsigned short* Asrc = (kc < 4) ? A1 : A2;
        int kOff = (kc & 3) * 32;
        int node = nodeBase + r;
        float4 av = make_float4(0.f, 0.f, 0.f, 0.f);
        if (node < N_NODES) av = *(const float4*)(Asrc + node * 128 + kOff + sg * 8);
        *(float4*)(&Asm[r][sg * 8]) = av;
        #pragma unroll
        for (int it = 0; it < 2; ++it) {      // W staging: 128 rows x 4 x 16B
            int idx = tid + it * 256;
            int wr = idx >> 2, wsg = idx & 3;
            *(float4*)(&Wsm[wr][wsg * 8]) = *(const float4*)(Wcat + wr * 256 + kc * 32 + wsg * 8);
        }
        __syncthreads();
        short8 afr[4], bfr[2];
        #pragma unroll
        for (int nb = 0; nb < 4; ++nb)
            afr[nb] = *(const short8*)(&Asm[nb * 16 + m][quad * 8]);
        #pragma unroll
        for (int cb = 0; cb < 2; ++cb)
            bfr[cb] = *(const short8*)(&Wsm[wave * 32 + cb * 16 + m][quad * 8]);
        #pragma unroll
        for (int nb = 0; nb < 4; ++nb)
            #pragma unroll
            for (int cb = 0; cb < 2; ++cb)
                acc[nb][cb] = __builtin_amdgcn_mfma_f32_16x16x32_bf16(afr[nb], bfr[cb], acc[nb][cb], 0, 0, 0);
        __syncthreads();
    }
    // epilogue: C layout col=lane&15, row=quad*4+reg
    #pragma unroll
    for (int cb = 0; cb < 2; ++cb) {
        int col = wave * 32 + cb * 16 + m;
        float bv = bias[col];
        #pragma unroll
        for (int nb = 0; nb < 4; ++nb) {
            #pragma unroll
            for (int rr = 0; rr < 4; ++rr) {
                int row = nodeBase + nb * 16 + quad * 4 + rr;
                if (row < N_NODES) {
                    float v = acc[nb][cb][rr] + bv;
                    v = v > 0.f ? v : 0.f;
                    out[row * 128 + col] = f2bf(v);
                }
            }
        }
    }
}

// ---- global_add_pool (batch sorted -> binary search) + LayerNorm + linear head ----
__global__ void pool_ln_out_kernel(const unsigned short* __restrict__ h2,
                                   const int* __restrict__ batch,
                                   const float* __restrict__ ln_g, const float* __restrict__ ln_b,
                                   const float* __restrict__ Wlin, const float* __restrict__ blin,
                                   float* __restrict__ out) {
    int g = blockIdx.x;
    int c = threadIdx.x;   // 128 threads
    __shared__ int se[2];
    if (c < 2) {
        int target = g + c;
        int lo = 0, hi = N_NODES;
        while (lo < hi) {
            int mid = (lo + hi) >> 1;
            if (batch[mid] < target) lo = mid + 1; else hi = mid;
        }
        se[c] = lo;
    }
    __syncthreads();
    int s = se[0], e = se[1];
    float sum = 0.f;
    for (int n = s; n < e; ++n) sum += bf2f((unsigned int)h2[n * 128 + c]);

    __shared__ float red[128];
    red[c] = sum;
    for (int off = 64; off > 0; off >>= 1) { __syncthreads(); if (c < off) red[c] += red[c + off]; }
    __syncthreads();
    float mu = red[0] * (1.f / 128.f);
    __syncthreads();
    float dv = sum - mu;
    red[c] = dv * dv;
    for (int off = 64; off > 0; off >>= 1) { __syncthreads(); if (c < off) red[c] += red[c + off]; }
    __syncthreads();
    float var = red[0] * (1.f / 128.f);
    float gn = dv * rsqrtf(var + LN_EPS) * ln_g[c] + ln_b[c];

    __shared__ float r0[128], r1[128];
    r0[c] = gn * Wlin[c];
    r1[c] = gn * Wlin[128 + c];
    for (int off = 64; off > 0; off >>= 1) {
        __syncthreads();
        if (c < off) { r0[c] += r0[c + off]; r1[c] += r1[c + off]; }
    }
    __syncthreads();
    if (c == 0) {
        out[g * 2 + 0] = r0[0] + blin[0];
        out[g * 2 + 1] = r1[0] + blin[1];
    }
}

extern "C" void kernel_launch(void* const* d_in, const int* in_sizes, int n_in,
                              void* d_out, int out_size, void* d_ws, size_t ws_size,
                              hipStream_t stream) {
    const float* x    = (const float*)d_in[0];
    const int*   ei   = (const int*)d_in[1];
    const int*   batch= (const int*)d_in[2];
    const float* W1l  = (const float*)d_in[3];
    const float* b1l  = (const float*)d_in[4];
    const float* W1r  = (const float*)d_in[5];
    const float* W2l  = (const float*)d_in[6];
    const float* b2l  = (const float*)d_in[7];
    const float* W2r  = (const float*)d_in[8];
    const float* ln_g = (const float*)d_in[9];
    const float* ln_b = (const float*)d_in[10];
    const float* Wlin = (const float*)d_in[11];
    const float* blin = (const float*)d_in[12];
    float* out = (float*)d_out;

    char* ws = (char*)d_ws;
    size_t off = 0;
    auto alloc = [&](size_t bytes) {
        char* p = ws + off;
        off = (off + bytes + 255) & ~(size_t)255;
        return p;
    };
    unsigned short* xbf  = (unsigned short*)alloc((size_t)N_NODES * D * 2); // later reused for h2
    unsigned short* aggb = (unsigned short*)alloc((size_t)N_NODES * D * 2);
    unsigned short* h1   = (unsigned short*)alloc((size_t)N_NODES * D * 2);
    unsigned short* Wc1  = (unsigned short*)alloc(128 * 256 * 2);
    unsigned short* Wc2  = (unsigned short*)alloc(128 * 256 * 2);
    int* deg        = (int*)alloc((size_t)N_NODES * 4);
    int* row_start  = (int*)alloc((size_t)(N_NODES + 1) * 4);
    int* cursor     = (int*)alloc((size_t)N_NODES * 4);
    int* src_sorted = (int*)alloc((size_t)N_EDGES * 4);
    int* bsum       = (int*)alloc(NSCAN_BLK * 4);
    int* boff       = (int*)alloc(NSCAN_BLK * 4);

    const int* srcI = ei;            // edge_index[0]
    const int* dstI = ei + N_EDGES;  // edge_index[1]

    hipMemsetAsync(deg, 0, (size_t)N_NODES * 4, stream);
    cvt_weights_kernel<<<256, 256, 0, stream>>>(W1l, W1r, W2l, W2r, Wc1, Wc2);
    cvt_x_kernel<<<12500, 256, 0, stream>>>(x, xbf);
    hist_kernel<<<6250, 256, 0, stream>>>(dstI, deg);
    scan1_kernel<<<NSCAN_BLK, 256, 0, stream>>>(deg, bsum);
    scan2_kernel<<<1, 512, 0, stream>>>(bsum, boff, row_start);
    scan3_kernel<<<NSCAN_BLK, 256, 0, stream>>>(deg, boff, row_start, cursor);
    scatter_kernel<<<6250, 256, 0, stream>>>(srcI, dstI, cursor, src_sorted);

    aggregate_kernel<<<25000, 256, 0, stream>>>(xbf, src_sorted, row_start, aggb);
    gemm_kernel<<<1563, 256, 0, stream>>>(aggb, xbf, Wc1, b1l, h1);
    aggregate_kernel<<<25000, 256, 0, stream>>>(h1, src_sorted, row_start, aggb);
    gemm_kernel<<<1563, 256, 0, stream>>>(aggb, h1, Wc2, b2l, xbf);   // h2 -> xbf (x consumed)
    pool_ln_out_kernel<<<NUM_GRAPHS, 128, 0, stream>>>(xbf, batch, ln_g, ln_b, Wlin, blin, out);
}

// Round 2
// 452.641 us; speedup vs baseline: 1.3008x; 1.3008x over previous
//
#include <hip/hip_runtime.h>
#include <hip/hip_bf16.h>

#define N_NODES   100000
#define N_EDGES   1600000
#define NUM_GRAPHS 1024
#define D         128
#define LN_EPS    1e-5f
#define NBUCKETS  196     // buckets of 512 nodes: bucket = dst >> 9
#define CHUNK     4096    // edges per bin_scatter block

typedef __attribute__((ext_vector_type(8))) short short8;
typedef __attribute__((ext_vector_type(4))) float floatx4;

static __device__ __forceinline__ float bf2f(unsigned int u) {
    return __uint_as_float(u << 16);
}
static __device__ __forceinline__ unsigned short f2bf(float f) {
    __hip_bfloat16 h = __float2bfloat16(f);
    return *reinterpret_cast<unsigned short*>(&h);
}

// ---- weight prep: Wcat[c][k] = k<128 ? Wl[c][k] : Wr[c][k-128], fp32 -> bf16 ----
__global__ void cvt_weights_kernel(const float* __restrict__ W1l, const float* __restrict__ W1r,
                                   const float* __restrict__ W2l, const float* __restrict__ W2r,
                                   unsigned short* __restrict__ Wc1, unsigned short* __restrict__ Wc2) {
    int idx = blockIdx.x * 256 + threadIdx.x;   // 0..65535 (2 layers x 128 x 256)
    int layer = idx >> 15;
    int rem = idx & 32767;
    int c = rem >> 8;
    int k = rem & 255;
    const float* Wl = layer ? W2l : W1l;
    const float* Wr = layer ? W2r : W1r;
    unsigned short* dst = layer ? Wc2 : Wc1;
    float v = (k < 128) ? Wl[c * 128 + k] : Wr[c * 128 + (k - 128)];
    dst[c * 256 + k] = f2bf(v);
}

// ---- x fp32 -> bf16 (vectorized float4 -> ushort4) ----
__global__ void cvt_x_kernel(const float* __restrict__ x, unsigned short* __restrict__ xbf) {
    int i = blockIdx.x * 256 + threadIdx.x;     // float4 index, 3.2M exact
    float4 v = reinterpret_cast<const float4*>(x)[i];
    ushort4 o;
    o.x = f2bf(v.x); o.y = f2bf(v.y); o.z = f2bf(v.z); o.w = f2bf(v.w);
    reinterpret_cast<ushort4*>(xbf)[i] = o;
}

// ---- CSR build, two-level binned counting sort ----
// Level-1 histogram: LDS per-block counts, one global atomic per (block,bucket).
__global__ __launch_bounds__(256)
void bin_count_kernel(const int* __restrict__ dst, int* __restrict__ bucket_count) {
    __shared__ int cnt[NBUCKETS];
    for (int i = threadIdx.x; i < NBUCKETS; i += 256) cnt[i] = 0;
    __syncthreads();
    int stride = gridDim.x * 256;
    for (int e = blockIdx.x * 256 + threadIdx.x; e < N_EDGES; e += stride)
        atomicAdd(&cnt[dst[e] >> 9], 1);
    __syncthreads();
    for (int i = threadIdx.x; i < NBUCKETS; i += 256) {
        int c = cnt[i];
        if (c) atomicAdd(&bucket_count[i], c);
    }
}

// Exclusive scan of 196 bucket counts; init cursors; CSR sentinel.
__global__ void bucket_scan_kernel(const int* __restrict__ bucket_count,
                                   int* __restrict__ bucket_base,
                                   int* __restrict__ bucket_cursor,
                                   int* __restrict__ row_start) {
    __shared__ int s[256];
    int t = threadIdx.x;
    int v = (t < NBUCKETS) ? bucket_count[t] : 0;
    s[t] = v;
    __syncthreads();
    for (int off = 1; off < 256; off <<= 1) {
        int a = (t >= off) ? s[t - off] : 0;
        __syncthreads();
        s[t] += a;
        __syncthreads();
    }
    if (t < NBUCKETS) {
        int b = s[t] - v;
        bucket_base[t] = b;
        bucket_cursor[t] = b;
    }
    if (t == 0) {
        bucket_base[NBUCKETS] = N_EDGES;
        row_start[N_NODES] = N_EDGES;
    }
}

// Scatter edges into bucket-major order. Per-block LDS offsets, one global
// atomic per (block,bucket); writes are bucket-contiguous runs (full lines).
__global__ __launch_bounds__(256)
void bin_scatter_kernel(const int* __restrict__ src, const int* __restrict__ dst,
                        int* __restrict__ bucket_cursor, uint2* __restrict__ binned) {
    __shared__ int cnt[NBUCKETS];
    __shared__ int base[NBUCKETS];
    int chunkBase = blockIdx.x * CHUNK;
    for (int i = threadIdx.x; i < NBUCKETS; i += 256) cnt[i] = 0;
    __syncthreads();
    int es[16], ed[16], lofs[16];
    #pragma unroll
    for (int j = 0; j < 16; ++j) {
        int e = chunkBase + j * 256 + threadIdx.x;
        if (e < N_EDGES) {
            es[j] = src[e];
            ed[j] = dst[e];
            lofs[j] = atomicAdd(&cnt[ed[j] >> 9], 1);
        }
    }
    __syncthreads();
    for (int i = threadIdx.x; i < NBUCKETS; i += 256) {
        int c = cnt[i];
        base[i] = c ? atomicAdd(&bucket_cursor[i], c) : 0;
    }
    __syncthreads();
    #pragma unroll
    for (int j = 0; j < 16; ++j) {
        int e = chunkBase + j * 256 + threadIdx.x;
        if (e < N_EDGES) {
            int b = ed[j] >> 9;
            binned[base[b] + lofs[j]] = make_uint2((unsigned)es[j], (unsigned)ed[j]);
        }
    }
}

// One block per bucket: per-node counts/scan/cursors in LDS; emit row_start
// and src_sorted (contiguous ~64KB window per block -> L2 resident).
__global__ __launch_bounds__(512)
void bucket_build_kernel(const uint2* __restrict__ binned, const int* __restrict__ bucket_base,
                         int* __restrict__ row_start, int* __restrict__ src_sorted) {
    __shared__ int scnt[512];
    __shared__ int sscan[512];
    int b = blockIdx.x;
    int t = threadIdx.x;
    int lo = bucket_base[b], hi = bucket_base[b + 1];
    scnt[t] = 0;
    __syncthreads();
    for (int e = lo + t; e < hi; e += 512)
        atomicAdd(&scnt[binned[e].y & 511], 1);
    __syncthreads();
    int v = scnt[t];
    sscan[t] = v;
    __syncthreads();
    for (int off = 1; off < 512; off <<= 1) {
        int a = (t >= off) ? sscan[t - off] : 0;
        __syncthreads();
        sscan[t] += a;
        __syncthreads();
    }
    int ex = sscan[t] - v;          // exclusive prefix within bucket
    int node = b * 512 + t;
    if (node < N_NODES) row_start[node] = lo + ex;
    scnt[t] = ex;                    // reuse as cursor
    __syncthreads();
    for (int e = lo + t; e < hi; e += 512) {
        uint2 r = binned[e];
        int p = atomicAdd(&scnt[r.y & 511], 1);
        src_sorted[lo + p] = (int)r.x;
    }
}

// ---- mean aggregation by gather: one wave per node, lane holds 2 channels ----
__global__ void aggregate_kernel(const unsigned short* __restrict__ feat,
                                 const int* __restrict__ src_sorted,
                                 const int* __restrict__ row_start,
                                 unsigned short* __restrict__ aggout) {
    int wave = threadIdx.x >> 6;
    int lane = threadIdx.x & 63;
    int node = blockIdx.x * 4 + wave;
    if (node >= N_NODES) return;
    int s = row_start[node];
    int e = row_start[node + 1];
    float ax = 0.f, ay = 0.f;
    int j = s;
    for (; j + 1 < e; j += 2) {
        int u0 = src_sorted[j];
        int u1 = src_sorted[j + 1];
        unsigned int v0 = *(const unsigned int*)(feat + u0 * 128 + lane * 2);
        unsigned int v1 = *(const unsigned int*)(feat + u1 * 128 + lane * 2);
        ax += bf2f(v0 & 0xffffu) + bf2f(v1 & 0xffffu);
        ay += bf2f(v0 >> 16)     + bf2f(v1 >> 16);
    }
    if (j < e) {
        int u = src_sorted[j];
        unsigned int v = *(const unsigned int*)(feat + u * 128 + lane * 2);
        ax += bf2f(v & 0xffffu);
        ay += bf2f(v >> 16);
    }
    int dgi = e - s;
    float inv = 1.f / (float)(dgi > 1 ? dgi : 1);
    unsigned int packed = (unsigned int)f2bf(ax * inv) | ((unsigned int)f2bf(ay * inv) << 16);
    *(unsigned int*)(aggout + node * 128 + lane * 2) = packed;
}

// ---- fused SAGE linear: out = relu([A1|A2] @ Wcat^T + bias), bf16 MFMA ----
__global__ __launch_bounds__(256)
void gemm_kernel(const unsigned short* __restrict__ A1,   // k 0..127   (agg)
                 const unsigned short* __restrict__ A2,   // k 128..255 (self)
                 const unsigned short* __restrict__ Wcat, // [128][256] bf16 (B^T form)
                 const float* __restrict__ bias,
                 unsigned short* __restrict__ out) {
    __shared__ unsigned short Asm[64][32];
    __shared__ unsigned short Wsm[128][32];
    int tid = threadIdx.x;
    int wave = tid >> 6;
    int lane = tid & 63;
    int nodeBase = blockIdx.x * 64;
    floatx4 acc[4][2];
    #pragma unroll
    for (int a = 0; a < 4; ++a)
        #pragma unroll
        for (int b = 0; b < 2; ++b) acc[a][b] = (floatx4){0.f, 0.f, 0.f, 0.f};

    int r = tid >> 2, sg = tid & 3;
    int quad = lane >> 4, m = lane & 15;

    for (int kc = 0; kc < 8; ++kc) {
        const unsigned short* Asrc = (kc < 4) ? A1 : A2;
        int kOff = (kc & 3) * 32;
        int node = nodeBase + r;
        float4 av = make_float4(0.f, 0.f, 0.f, 0.f);
        if (node < N_NODES) av = *(const float4*)(Asrc + node * 128 + kOff + sg * 8);
        *(float4*)(&Asm[r][sg * 8]) = av;
        #pragma unroll
        for (int it = 0; it < 2; ++it) {
            int idx = tid + it * 256;
            int wr = idx >> 2, wsg = idx & 3;
            *(float4*)(&Wsm[wr][wsg * 8]) = *(const float4*)(Wcat + wr * 256 + kc * 32 + wsg * 8);
        }
        __syncthreads();
        short8 afr[4], bfr[2];
        #pragma unroll
        for (int nb = 0; nb < 4; ++nb)
            afr[nb] = *(const short8*)(&Asm[nb * 16 + m][quad * 8]);
        #pragma unroll
        for (int cb = 0; cb < 2; ++cb)
            bfr[cb] = *(const short8*)(&Wsm[wave * 32 + cb * 16 + m][quad * 8]);
        #pragma unroll
        for (int nb = 0; nb < 4; ++nb)
            #pragma unroll
            for (int cb = 0; cb < 2; ++cb)
                acc[nb][cb] = __builtin_amdgcn_mfma_f32_16x16x32_bf16(afr[nb], bfr[cb], acc[nb][cb], 0, 0, 0);
        __syncthreads();
    }
    #pragma unroll
    for (int cb = 0; cb < 2; ++cb) {
        int col = wave * 32 + cb * 16 + m;
        float bv = bias[col];
        #pragma unroll
        for (int nb = 0; nb < 4; ++nb) {
            #pragma unroll
            for (int rr = 0; rr < 4; ++rr) {
                int row = nodeBase + nb * 16 + quad * 4 + rr;
                if (row < N_NODES) {
                    float v = acc[nb][cb][rr] + bv;
                    v = v > 0.f ? v : 0.f;
                    out[row * 128 + col] = f2bf(v);
                }
            }
        }
    }
}

// ---- global_add_pool (batch sorted -> binary search) + LayerNorm + linear head ----
__global__ void pool_ln_out_kernel(const unsigned short* __restrict__ h2,
                                   const int* __restrict__ batch,
                                   const float* __restrict__ ln_g, const float* __restrict__ ln_b,
                                   const float* __restrict__ Wlin, const float* __restrict__ blin,
                                   float* __restrict__ out) {
    int g = blockIdx.x;
    int c = threadIdx.x;   // 128 threads
    __shared__ int se[2];
    if (c < 2) {
        int target = g + c;
        int lo = 0, hi = N_NODES;
        while (lo < hi) {
            int mid = (lo + hi) >> 1;
            if (batch[mid] < target) lo = mid + 1; else hi = mid;
        }
        se[c] = lo;
    }
    __syncthreads();
    int s = se[0], e = se[1];
    float sum = 0.f;
    for (int n = s; n < e; ++n) sum += bf2f((unsigned int)h2[n * 128 + c]);

    __shared__ float red[128];
    red[c] = sum;
    for (int off = 64; off > 0; off >>= 1) { __syncthreads(); if (c < off) red[c] += red[c + off]; }
    __syncthreads();
    float mu = red[0] * (1.f / 128.f);
    __syncthreads();
    float dv = sum - mu;
    red[c] = dv * dv;
    for (int off = 64; off > 0; off >>= 1) { __syncthreads(); if (c < off) red[c] += red[c + off]; }
    __syncthreads();
    float var = red[0] * (1.f / 128.f);
    float gn = dv * rsqrtf(var + LN_EPS) * ln_g[c] + ln_b[c];

    __shared__ float r0[128], r1[128];
    r0[c] = gn * Wlin[c];
    r1[c] = gn * Wlin[128 + c];
    for (int off = 64; off > 0; off >>= 1) {
        __syncthreads();
        if (c < off) { r0[c] += r0[c + off]; r1[c] += r1[c + off]; }
    }
    __syncthreads();
    if (c == 0) {
        out[g * 2 + 0] = r0[0] + blin[0];
        out[g * 2 + 1] = r1[0] + blin[1];
    }
}

extern "C" void kernel_launch(void* const* d_in, const int* in_sizes, int n_in,
                              void* d_out, int out_size, void* d_ws, size_t ws_size,
                              hipStream_t stream) {
    const float* x    = (const float*)d_in[0];
    const int*   ei   = (const int*)d_in[1];
    const int*   batch= (const int*)d_in[2];
    const float* W1l  = (const float*)d_in[3];
    const float* b1l  = (const float*)d_in[4];
    const float* W1r  = (const float*)d_in[5];
    const float* W2l  = (const float*)d_in[6];
    const float* b2l  = (const float*)d_in[7];
    const float* W2r  = (const float*)d_in[8];
    const float* ln_g = (const float*)d_in[9];
    const float* ln_b = (const float*)d_in[10];
    const float* Wlin = (const float*)d_in[11];
    const float* blin = (const float*)d_in[12];
    float* out = (float*)d_out;

    char* ws = (char*)d_ws;
    size_t off = 0;
    auto alloc = [&](size_t bytes) {
        char* p = ws + off;
        off = (off + bytes + 255) & ~(size_t)255;
        return p;
    };
    unsigned short* xbf  = (unsigned short*)alloc((size_t)N_NODES * D * 2); // later reused for h2
    unsigned short* aggb = (unsigned short*)alloc((size_t)N_NODES * D * 2); // aliased by binned
    unsigned short* h1   = (unsigned short*)alloc((size_t)N_NODES * D * 2);
    unsigned short* Wc1  = (unsigned short*)alloc(128 * 256 * 2);
    unsigned short* Wc2  = (unsigned short*)alloc(128 * 256 * 2);
    int* row_start     = (int*)alloc((size_t)(N_NODES + 1) * 4);
    int* src_sorted    = (int*)alloc((size_t)N_EDGES * 4);
    int* bucket_count  = (int*)alloc(NBUCKETS * 4);
    int* bucket_base   = (int*)alloc((NBUCKETS + 1) * 4);
    int* bucket_cursor = (int*)alloc(NBUCKETS * 4);
    uint2* binned = (uint2*)aggb;   // 12.8 MB <= 25.6 MB; consumed before aggb written

    const int* srcI = ei;            // edge_index[0]
    const int* dstI = ei + N_EDGES;  // edge_index[1]

    hipMemsetAsync(bucket_count, 0, NBUCKETS * 4, stream);
    cvt_weights_kernel<<<256, 256, 0, stream>>>(W1l, W1r, W2l, W2r, Wc1, Wc2);
    cvt_x_kernel<<<12500, 256, 0, stream>>>(x, xbf);

    bin_count_kernel<<<512, 256, 0, stream>>>(dstI, bucket_count);
    bucket_scan_kernel<<<1, 256, 0, stream>>>(bucket_count, bucket_base, bucket_cursor, row_start);
    bin_scatter_kernel<<<(N_EDGES + CHUNK - 1) / CHUNK, 256, 0, stream>>>(srcI, dstI, bucket_cursor, binned);
    bucket_build_kernel<<<NBUCKETS, 512, 0, stream>>>(binned, bucket_base, row_start, src_sorted);

    aggregate_kernel<<<25000, 256, 0, stream>>>(xbf, src_sorted, row_start, aggb);
    gemm_kernel<<<1563, 256, 0, stream>>>(aggb, xbf, Wc1, b1l, h1);
    aggregate_kernel<<<25000, 256, 0, stream>>>(h1, src_sorted, row_start, aggb);
    gemm_kernel<<<1563, 256, 0, stream>>>(aggb, h1, Wc2, b2l, xbf);
    pool_ln_out_kernel<<<NUM_GRAPHS, 128, 0, stream>>>(xbf, batch, ln_g, ln_b, Wlin, blin, out);
}

// Round 3
// 381.287 us; speedup vs baseline: 1.5443x; 1.1871x over previous
//
#include <hip/hip_runtime.h>
#include <hip/hip_bf16.h>

#define N_NODES   100000
#define N_EDGES   1600000
#define NUM_GRAPHS 1024
#define D         128
#define LN_EPS    1e-5f
#define NBUCKETS  196     // buckets of 512 nodes: bucket = dst >> 9
#define CHUNK     4096    // edges per bin_scatter block

typedef __attribute__((ext_vector_type(8))) short short8;
typedef __attribute__((ext_vector_type(4))) float floatx4;

static __device__ __forceinline__ float bf2f(unsigned int u) {
    return __uint_as_float(u << 16);
}
static __device__ __forceinline__ unsigned short f2bf(float f) {
    __hip_bfloat16 h = __float2bfloat16(f);
    return *reinterpret_cast<unsigned short*>(&h);
}

// ---- weight prep: Wcat[c][k] = k<128 ? Wl[c][k] : Wr[c][k-128], fp32 -> bf16 ----
__global__ void cvt_weights_kernel(const float* __restrict__ W1l, const float* __restrict__ W1r,
                                   const float* __restrict__ W2l, const float* __restrict__ W2r,
                                   unsigned short* __restrict__ Wc1, unsigned short* __restrict__ Wc2) {
    int idx = blockIdx.x * 256 + threadIdx.x;   // 0..65535 (2 layers x 128 x 256)
    int layer = idx >> 15;
    int rem = idx & 32767;
    int c = rem >> 8;
    int k = rem & 255;
    const float* Wl = layer ? W2l : W1l;
    const float* Wr = layer ? W2r : W1r;
    unsigned short* dst = layer ? Wc2 : Wc1;
    float v = (k < 128) ? Wl[c * 128 + k] : Wr[c * 128 + (k - 128)];
    dst[c * 256 + k] = f2bf(v);
}

// ---- x fp32 -> bf16 (vectorized float4 -> ushort4) ----
__global__ void cvt_x_kernel(const float* __restrict__ x, unsigned short* __restrict__ xbf) {
    int i = blockIdx.x * 256 + threadIdx.x;     // float4 index, 3.2M exact
    float4 v = reinterpret_cast<const float4*>(x)[i];
    ushort4 o;
    o.x = f2bf(v.x); o.y = f2bf(v.y); o.z = f2bf(v.z); o.w = f2bf(v.w);
    reinterpret_cast<ushort4*>(xbf)[i] = o;
}

// ---- CSR build, two-level binned counting sort ----
__global__ __launch_bounds__(256)
void bin_count_kernel(const int* __restrict__ dst, int* __restrict__ bucket_count) {
    __shared__ int cnt[NBUCKETS];
    for (int i = threadIdx.x; i < NBUCKETS; i += 256) cnt[i] = 0;
    __syncthreads();
    int stride = gridDim.x * 256;
    for (int e = blockIdx.x * 256 + threadIdx.x; e < N_EDGES; e += stride)
        atomicAdd(&cnt[dst[e] >> 9], 1);
    __syncthreads();
    for (int i = threadIdx.x; i < NBUCKETS; i += 256) {
        int c = cnt[i];
        if (c) atomicAdd(&bucket_count[i], c);
    }
}

__global__ void bucket_scan_kernel(const int* __restrict__ bucket_count,
                                   int* __restrict__ bucket_base,
                                   int* __restrict__ bucket_cursor,
                                   int* __restrict__ row_start) {
    __shared__ int s[256];
    int t = threadIdx.x;
    int v = (t < NBUCKETS) ? bucket_count[t] : 0;
    s[t] = v;
    __syncthreads();
    for (int off = 1; off < 256; off <<= 1) {
        int a = (t >= off) ? s[t - off] : 0;
        __syncthreads();
        s[t] += a;
        __syncthreads();
    }
    if (t < NBUCKETS) {
        int b = s[t] - v;
        bucket_base[t] = b;
        bucket_cursor[t] = b;
    }
    if (t == 0) {
        bucket_base[NBUCKETS] = N_EDGES;
        row_start[N_NODES] = N_EDGES;
    }
}

__global__ __launch_bounds__(256)
void bin_scatter_kernel(const int* __restrict__ src, const int* __restrict__ dst,
                        int* __restrict__ bucket_cursor, uint2* __restrict__ binned) {
    __shared__ int cnt[NBUCKETS];
    __shared__ int base[NBUCKETS];
    int chunkBase = blockIdx.x * CHUNK;
    for (int i = threadIdx.x; i < NBUCKETS; i += 256) cnt[i] = 0;
    __syncthreads();
    int es[16], ed[16], lofs[16];
    #pragma unroll
    for (int j = 0; j < 16; ++j) {
        int e = chunkBase + j * 256 + threadIdx.x;
        if (e < N_EDGES) {
            es[j] = src[e];
            ed[j] = dst[e];
            lofs[j] = atomicAdd(&cnt[ed[j] >> 9], 1);
        }
    }
    __syncthreads();
    for (int i = threadIdx.x; i < NBUCKETS; i += 256) {
        int c = cnt[i];
        base[i] = c ? atomicAdd(&bucket_cursor[i], c) : 0;
    }
    __syncthreads();
    #pragma unroll
    for (int j = 0; j < 16; ++j) {
        int e = chunkBase + j * 256 + threadIdx.x;
        if (e < N_EDGES) {
            int b = ed[j] >> 9;
            binned[base[b] + lofs[j]] = make_uint2((unsigned)es[j], (unsigned)ed[j]);
        }
    }
}

__global__ __launch_bounds__(512)
void bucket_build_kernel(const uint2* __restrict__ binned, const int* __restrict__ bucket_base,
                         int* __restrict__ row_start, int* __restrict__ src_sorted) {
    __shared__ int scnt[512];
    __shared__ int sscan[512];
    int b = blockIdx.x;
    int t = threadIdx.x;
    int lo = bucket_base[b], hi = bucket_base[b + 1];
    scnt[t] = 0;
    __syncthreads();
    for (int e = lo + t; e < hi; e += 512)
        atomicAdd(&scnt[binned[e].y & 511], 1);
    __syncthreads();
    int v = scnt[t];
    sscan[t] = v;
    __syncthreads();
    for (int off = 1; off < 512; off <<= 1) {
        int a = (t >= off) ? sscan[t - off] : 0;
        __syncthreads();
        sscan[t] += a;
        __syncthreads();
    }
    int ex = sscan[t] - v;
    int node = b * 512 + t;
    if (node < N_NODES) row_start[node] = lo + ex;
    scnt[t] = ex;
    __syncthreads();
    for (int e = lo + t; e < hi; e += 512) {
        uint2 r = binned[e];
        int p = atomicAdd(&scnt[r.y & 511], 1);
        src_sorted[lo + p] = (int)r.x;
    }
}

// ---- mean aggregation by gather: wave handles 4 edges/load-inst ----
// lane l: edge subgroup sub=l>>4, channels ch=(l&15)*8 (16 B dwordx4).
// Unroll x2 -> 8 row-gathers in flight per wave. Cross-subgroup reduce via
// __shfl_xor(16|32), lanes sub==0 write the bf16 row.
__global__ __launch_bounds__(256)
void aggregate_kernel(const unsigned short* __restrict__ feat,
                      const int* __restrict__ src_sorted,
                      const int* __restrict__ row_start,
                      unsigned short* __restrict__ aggout) {
    int wave = threadIdx.x >> 6;
    int lane = threadIdx.x & 63;
    int node = blockIdx.x * 4 + wave;
    int sub = lane >> 4;
    int ch = (lane & 15) * 8;
    int s = row_start[node];
    int e = row_start[node + 1];
    float acc[8];
    #pragma unroll
    for (int i = 0; i < 8; ++i) acc[i] = 0.f;

    int j = s + sub;
    for (; j + 4 < e; j += 8) {
        int u0 = src_sorted[j];
        int u1 = src_sorted[j + 4];
        uint4 v0 = *(const uint4*)(feat + (size_t)u0 * 128 + ch);
        uint4 v1 = *(const uint4*)(feat + (size_t)u1 * 128 + ch);
        acc[0] += __uint_as_float(v0.x << 16);
        acc[1] += __uint_as_float(v0.x & 0xffff0000u);
        acc[2] += __uint_as_float(v0.y << 16);
        acc[3] += __uint_as_float(v0.y & 0xffff0000u);
        acc[4] += __uint_as_float(v0.z << 16);
        acc[5] += __uint_as_float(v0.z & 0xffff0000u);
        acc[6] += __uint_as_float(v0.w << 16);
        acc[7] += __uint_as_float(v0.w & 0xffff0000u);
        acc[0] += __uint_as_float(v1.x << 16);
        acc[1] += __uint_as_float(v1.x & 0xffff0000u);
        acc[2] += __uint_as_float(v1.y << 16);
        acc[3] += __uint_as_float(v1.y & 0xffff0000u);
        acc[4] += __uint_as_float(v1.z << 16);
        acc[5] += __uint_as_float(v1.z & 0xffff0000u);
        acc[6] += __uint_as_float(v1.w << 16);
        acc[7] += __uint_as_float(v1.w & 0xffff0000u);
    }
    if (j < e) {
        int u = src_sorted[j];
        uint4 v = *(const uint4*)(feat + (size_t)u * 128 + ch);
        acc[0] += __uint_as_float(v.x << 16);
        acc[1] += __uint_as_float(v.x & 0xffff0000u);
        acc[2] += __uint_as_float(v.y << 16);
        acc[3] += __uint_as_float(v.y & 0xffff0000u);
        acc[4] += __uint_as_float(v.z << 16);
        acc[5] += __uint_as_float(v.z & 0xffff0000u);
        acc[6] += __uint_as_float(v.w << 16);
        acc[7] += __uint_as_float(v.w & 0xffff0000u);
    }
    // reduce the 4 edge-subgroups (lanes xor 16, 32)
    #pragma unroll
    for (int i = 0; i < 8; ++i) {
        acc[i] += __shfl_xor(acc[i], 16, 64);
        acc[i] += __shfl_xor(acc[i], 32, 64);
    }
    int dgi = e - s;
    float inv = 1.f / (float)(dgi > 1 ? dgi : 1);
    if (sub == 0) {
        uint4 ov;
        ov.x = (unsigned)f2bf(acc[0] * inv) | ((unsigned)f2bf(acc[1] * inv) << 16);
        ov.y = (unsigned)f2bf(acc[2] * inv) | ((unsigned)f2bf(acc[3] * inv) << 16);
        ov.z = (unsigned)f2bf(acc[4] * inv) | ((unsigned)f2bf(acc[5] * inv) << 16);
        ov.w = (unsigned)f2bf(acc[6] * inv) | ((unsigned)f2bf(acc[7] * inv) << 16);
        *(uint4*)(aggout + (size_t)node * 128 + ch) = ov;
    }
}

// ---- fused SAGE linear: out = relu([A1|A2] @ Wcat^T + bias), bf16 MFMA ----
__global__ __launch_bounds__(256)
void gemm_kernel(const unsigned short* __restrict__ A1,   // k 0..127   (agg)
                 const unsigned short* __restrict__ A2,   // k 128..255 (self)
                 const unsigned short* __restrict__ Wcat, // [128][256] bf16 (B^T form)
                 const float* __restrict__ bias,
                 unsigned short* __restrict__ out) {
    __shared__ unsigned short Asm[64][32];
    __shared__ unsigned short Wsm[128][32];
    int tid = threadIdx.x;
    int wave = tid >> 6;
    int lane = tid & 63;
    int nodeBase = blockIdx.x * 64;
    floatx4 acc[4][2];
    #pragma unroll
    for (int a = 0; a < 4; ++a)
        #pragma unroll
        for (int b = 0; b < 2; ++b) acc[a][b] = (floatx4){0.f, 0.f, 0.f, 0.f};

    int r = tid >> 2, sg = tid & 3;
    int quad = lane >> 4, m = lane & 15;

    for (int kc = 0; kc < 8; ++kc) {
        const unsigned short* Asrc = (kc < 4) ? A1 : A2;
        int kOff = (kc & 3) * 32;
        int node = nodeBase + r;
        float4 av = make_float4(0.f, 0.f, 0.f, 0.f);
        if (node < N_NODES) av = *(const float4*)(Asrc + node * 128 + kOff + sg * 8);
        *(float4*)(&Asm[r][sg * 8]) = av;
        #pragma unroll
        for (int it = 0; it < 2; ++it) {
            int idx = tid + it * 256;
            int wr = idx >> 2, wsg = idx & 3;
            *(float4*)(&Wsm[wr][wsg * 8]) = *(const float4*)(Wcat + wr * 256 + kc * 32 + wsg * 8);
        }
        __syncthreads();
        short8 afr[4], bfr[2];
        #pragma unroll
        for (int nb = 0; nb < 4; ++nb)
            afr[nb] = *(const short8*)(&Asm[nb * 16 + m][quad * 8]);
        #pragma unroll
        for (int cb = 0; cb < 2; ++cb)
            bfr[cb] = *(const short8*)(&Wsm[wave * 32 + cb * 16 + m][quad * 8]);
        #pragma unroll
        for (int nb = 0; nb < 4; ++nb)
            #pragma unroll
            for (int cb = 0; cb < 2; ++cb)
                acc[nb][cb] = __builtin_amdgcn_mfma_f32_16x16x32_bf16(afr[nb], bfr[cb], acc[nb][cb], 0, 0, 0);
        __syncthreads();
    }
    #pragma unroll
    for (int cb = 0; cb < 2; ++cb) {
        int col = wave * 32 + cb * 16 + m;
        float bv = bias[col];
        #pragma unroll
        for (int nb = 0; nb < 4; ++nb) {
            #pragma unroll
            for (int rr = 0; rr < 4; ++rr) {
                int row = nodeBase + nb * 16 + quad * 4 + rr;
                if (row < N_NODES) {
                    float v = acc[nb][cb][rr] + bv;
                    v = v > 0.f ? v : 0.f;
                    out[row * 128 + col] = f2bf(v);
                }
            }
        }
    }
}

// ---- global_add_pool (batch sorted -> binary search) + LayerNorm + linear head ----
__global__ void pool_ln_out_kernel(const unsigned short* __restrict__ h2,
                                   const int* __restrict__ batch,
                                   const float* __restrict__ ln_g, const float* __restrict__ ln_b,
                                   const float* __restrict__ Wlin, const float* __restrict__ blin,
                                   float* __restrict__ out) {
    int g = blockIdx.x;
    int c = threadIdx.x;   // 128 threads
    __shared__ int se[2];
    if (c < 2) {
        int target = g + c;
        int lo = 0, hi = N_NODES;
        while (lo < hi) {
            int mid = (lo + hi) >> 1;
            if (batch[mid] < target) lo = mid + 1; else hi = mid;
        }
        se[c] = lo;
    }
    __syncthreads();
    int s = se[0], e = se[1];
    float sum = 0.f;
    for (int n = s; n < e; ++n) sum += bf2f((unsigned int)h2[n * 128 + c]);

    __shared__ float red[128];
    red[c] = sum;
    for (int off = 64; off > 0; off >>= 1) { __syncthreads(); if (c < off) red[c] += red[c + off]; }
    __syncthreads();
    float mu = red[0] * (1.f / 128.f);
    __syncthreads();
    float dv = sum - mu;
    red[c] = dv * dv;
    for (int off = 64; off > 0; off >>= 1) { __syncthreads(); if (c < off) red[c] += red[c + off]; }
    __syncthreads();
    float var = red[0] * (1.f / 128.f);
    float gn = dv * rsqrtf(var + LN_EPS) * ln_g[c] + ln_b[c];

    __shared__ float r0[128], r1[128];
    r0[c] = gn * Wlin[c];
    r1[c] = gn * Wlin[128 + c];
    for (int off = 64; off > 0; off >>= 1) {
        __syncthreads();
        if (c < off) { r0[c] += r0[c + off]; r1[c] += r1[c + off]; }
    }
    __syncthreads();
    if (c == 0) {
        out[g * 2 + 0] = r0[0] + blin[0];
        out[g * 2 + 1] = r1[0] + blin[1];
    }
}

extern "C" void kernel_launch(void* const* d_in, const int* in_sizes, int n_in,
                              void* d_out, int out_size, void* d_ws, size_t ws_size,
                              hipStream_t stream) {
    const float* x    = (const float*)d_in[0];
    const int*   ei   = (const int*)d_in[1];
    const int*   batch= (const int*)d_in[2];
    const float* W1l  = (const float*)d_in[3];
    const float* b1l  = (const float*)d_in[4];
    const float* W1r  = (const float*)d_in[5];
    const float* W2l  = (const float*)d_in[6];
    const float* b2l  = (const float*)d_in[7];
    const float* W2r  = (const float*)d_in[8];
    const float* ln_g = (const float*)d_in[9];
    const float* ln_b = (const float*)d_in[10];
    const float* Wlin = (const float*)d_in[11];
    const float* blin = (const float*)d_in[12];
    float* out = (float*)d_out;

    char* ws = (char*)d_ws;
    size_t off = 0;
    auto alloc = [&](size_t bytes) {
        char* p = ws + off;
        off = (off + bytes + 255) & ~(size_t)255;
        return p;
    };
    unsigned short* xbf  = (unsigned short*)alloc((size_t)N_NODES * D * 2); // later reused for h2
    unsigned short* aggb = (unsigned short*)alloc((size_t)N_NODES * D * 2); // aliased by binned
    unsigned short* h1   = (unsigned short*)alloc((size_t)N_NODES * D * 2);
    unsigned short* Wc1  = (unsigned short*)alloc(128 * 256 * 2);
    unsigned short* Wc2  = (unsigned short*)alloc(128 * 256 * 2);
    int* row_start     = (int*)alloc((size_t)(N_NODES + 1) * 4);
    int* src_sorted    = (int*)alloc((size_t)N_EDGES * 4);
    int* bucket_count  = (int*)alloc(NBUCKETS * 4);
    int* bucket_base   = (int*)alloc((NBUCKETS + 1) * 4);
    int* bucket_cursor = (int*)alloc(NBUCKETS * 4);
    uint2* binned = (uint2*)aggb;   // 12.8 MB <= 25.6 MB; consumed before aggb written

    const int* srcI = ei;            // edge_index[0]
    const int* dstI = ei + N_EDGES;  // edge_index[1]

    hipMemsetAsync(bucket_count, 0, NBUCKETS * 4, stream);
    cvt_weights_kernel<<<256, 256, 0, stream>>>(W1l, W1r, W2l, W2r, Wc1, Wc2);
    cvt_x_kernel<<<12500, 256, 0, stream>>>(x, xbf);

    bin_count_kernel<<<512, 256, 0, stream>>>(dstI, bucket_count);
    bucket_scan_kernel<<<1, 256, 0, stream>>>(bucket_count, bucket_base, bucket_cursor, row_start);
    bin_scatter_kernel<<<(N_EDGES + CHUNK - 1) / CHUNK, 256, 0, stream>>>(srcI, dstI, bucket_cursor, binned);
    bucket_build_kernel<<<NBUCKETS, 512, 0, stream>>>(binned, bucket_base, row_start, src_sorted);

    aggregate_kernel<<<25000, 256, 0, stream>>>(xbf, src_sorted, row_start, aggb);
    gemm_kernel<<<1563, 256, 0, stream>>>(aggb, xbf, Wc1, b1l, h1);
    aggregate_kernel<<<25000, 256, 0, stream>>>(h1, src_sorted, row_start, aggb);
    gemm_kernel<<<1563, 256, 0, stream>>>(aggb, h1, Wc2, b2l, xbf);
    pool_ln_out_kernel<<<NUM_GRAPHS, 128, 0, stream>>>(xbf, batch, ln_g, ln_b, Wlin, blin, out);
}